// Round 8
// baseline (54.340 us; speedup 1.0000x reference)
//
#include <hip/hip_runtime.h>

#define EPS 1e-5f

static __device__ const int OFFS[8] = {0, 100000, 150000, 151000, 151500, 151600, 151650, 151670};

// ---- coherent-point 8B accesses (bypass non-coherent per-XCD L2) ----
__device__ __forceinline__ void st_f2(float* p, float a, float b) {
    union { float f[2]; unsigned long long u; } v;
    v.f[0] = a; v.f[1] = b;
    __hip_atomic_store((unsigned long long*)p, v.u, __ATOMIC_RELAXED, __HIP_MEMORY_SCOPE_AGENT);
}
__device__ __forceinline__ float2 ld_f2(const float* p) {
    union { unsigned long long u; float f[2]; } v;
    v.u = __hip_atomic_load((const unsigned long long*)p, __ATOMIC_RELAXED, __HIP_MEMORY_SCOPE_AGENT);
    return make_float2(v.f[0], v.f[1]);
}

// Store-based grid barrier for kernel B (256 blocks).
// Arrival: plain agent store flag[blk]=phase (no RMW -> no serialization).
// The preceding __syncthreads drains every wave's vmcnt, so all agent-scope
// data stores are at the coherence point before the flag store (R4/R5-validated).
// Detect: wave 0, each lane polls 4 flags; __all over 64 lanes.
#define BARRIER(ph) do {                                                                   \
    __syncthreads();                                                                       \
    if (t == 0)                                                                            \
        __hip_atomic_store(&flags[blk], (unsigned)(ph),                                    \
                           __ATOMIC_RELEASE, __HIP_MEMORY_SCOPE_AGENT);                    \
    if (t < 64) {                                                                          \
        for (;;) {                                                                         \
            unsigned f0 = __hip_atomic_load(&flags[t],       __ATOMIC_RELAXED, __HIP_MEMORY_SCOPE_AGENT); \
            unsigned f1 = __hip_atomic_load(&flags[t + 64],  __ATOMIC_RELAXED, __HIP_MEMORY_SCOPE_AGENT); \
            unsigned f2 = __hip_atomic_load(&flags[t + 128], __ATOMIC_RELAXED, __HIP_MEMORY_SCOPE_AGENT); \
            unsigned f3 = __hip_atomic_load(&flags[t + 192], __ATOMIC_RELAXED, __HIP_MEMORY_SCOPE_AGENT); \
            if (__all(f0 >= (unsigned)(ph) && f1 >= (unsigned)(ph) &&                      \
                      f2 >= (unsigned)(ph) && f3 >= (unsigned)(ph))) break;                \
            __builtin_amdgcn_s_sleep(4);                                                   \
        }                                                                                  \
    }                                                                                      \
    __syncthreads();                                                                       \
} while (0)

// ============================================================================
// A: 512 blocks x 256 thr. Block = (rt = blk>>1) 8 rows x (ch = blk&1) 128 cols.
// gather+FM (ch==0 writes yfm) -> h0 LDS -> GEMM1 (2r x 2c/thread, k-chunk 16)
// -> z1 + per-tile col partials p1. Block 0 zeroes the barrier flags for B.
// ============================================================================
__global__ __launch_bounds__(256) void kA_gather_fm_gemm1(
    const int* __restrict__ x, const float* __restrict__ emb,
    const float* __restrict__ wlin, const float* __restrict__ blin,
    const float* __restrict__ W1, const float* __restrict__ b1,
    float* __restrict__ yfm, float* __restrict__ z1, float* __restrict__ p1,
    unsigned* __restrict__ flags)
{
    __shared__ __align__(16) float h0s[8][128];
    __shared__ __align__(16) float redS[8][128];
    __shared__ __align__(16) float redQ[8][128];

    const int t = threadIdx.x;
    const int rt = blockIdx.x >> 1, ch = blockIdx.x & 1;

    if (blockIdx.x == 0) flags[t] = 0;     // plain store; kernel-end flush makes it visible

    // ---- gather + FM: 32 threads/row
    {
        const int r = t >> 5, c = t & 31;
        const int row = rt * 8 + r;
        const int f = c >> 2, dq = (c & 3) * 4;
        const int idxf = x[row * 8 + f];
        float4 e = *(const float4*)&emb[(size_t)(idxf + OFFS[f]) * 16 + dq];
        *(float4*)&h0s[r][f * 16 + dq] = e;

        if (ch == 0) {
            float4 s = e;
            float4 q = make_float4(e.x * e.x, e.y * e.y, e.z * e.z, e.w * e.w);
#pragma unroll
            for (int m = 4; m <= 16; m <<= 1) {
                s.x += __shfl_xor(s.x, m); s.y += __shfl_xor(s.y, m);
                s.z += __shfl_xor(s.z, m); s.w += __shfl_xor(s.w, m);
                q.x += __shfl_xor(q.x, m); q.y += __shfl_xor(q.y, m);
                q.z += __shfl_xor(q.z, m); q.w += __shfl_xor(q.w, m);
            }
            float pair = (s.x * s.x - q.x) + (s.y * s.y - q.y)
                       + (s.z * s.z - q.z) + (s.w * s.w - q.w);
            pair += __shfl_xor(pair, 1);
            pair += __shfl_xor(pair, 2);

            float lin = 0.f;
            if (c < 8) {
                int ids[8];
#pragma unroll
                for (int g = 0; g < 8; ++g) ids[g] = x[row * 8 + g];
                bool dup = false;
                for (int g = 0; g < c; ++g) dup = dup || (ids[g] == ids[c]);
                lin = dup ? 0.f : wlin[ids[c]];
            }
            lin += __shfl_xor(lin, 1);
            lin += __shfl_xor(lin, 2);
            lin += __shfl_xor(lin, 4);
            if (c == 0) yfm[row] = 0.5f * pair + lin + blin[0];
        }
    }
    __syncthreads();

    // ---- GEMM1: thread = rows {rg*2, rg*2+1} x cols {j, j+1}; k-chunks of 16
    const int cc = t & 63, rg = t >> 6;
    const int j = ch * 128 + cc * 2;
    const int r0 = rg * 2;
    float a00 = 0.f, a01 = 0.f, a10 = 0.f, a11 = 0.f;
#pragma unroll
    for (int k0 = 0; k0 < 128; k0 += 16) {
        float4 ha[4], hb[4];
#pragma unroll
        for (int i = 0; i < 4; ++i) {
            ha[i] = *(const float4*)&h0s[r0][k0 + i * 4];
            hb[i] = *(const float4*)&h0s[r0 + 1][k0 + i * 4];
        }
        float2 w[16];
#pragma unroll
        for (int kk = 0; kk < 16; ++kk)
            w[kk] = *(const float2*)&W1[(size_t)(k0 + kk) * 256 + j];
#pragma unroll
        for (int kk = 0; kk < 16; ++kk) {
            const float hva = ((const float*)ha)[kk];
            const float hvb = ((const float*)hb)[kk];
            a00 += hva * w[kk].x; a01 += hva * w[kk].y;
            a10 += hvb * w[kk].x; a11 += hvb * w[kk].y;
        }
    }
    float2 b2v = *(const float2*)&b1[j];
    float z00 = a00 + b2v.x, z01 = a01 + b2v.y;
    float z10 = a10 + b2v.x, z11 = a11 + b2v.y;
    *(float2*)&z1[(size_t)(rt * 8 + r0) * 256 + j]     = make_float2(z00, z01);
    *(float2*)&z1[(size_t)(rt * 8 + r0 + 1) * 256 + j] = make_float2(z10, z11);
    *(float2*)&redS[r0][cc * 2]     = make_float2(z00, z01);
    *(float2*)&redS[r0 + 1][cc * 2] = make_float2(z10, z11);
    *(float2*)&redQ[r0][cc * 2]     = make_float2(z00 * z00, z01 * z01);
    *(float2*)&redQ[r0 + 1][cc * 2] = make_float2(z10 * z10, z11 * z11);
    __syncthreads();
    if (t < 128) {
        float s = 0.f, q = 0.f;
#pragma unroll
        for (int rr = 0; rr < 8; ++rr) { s += redS[rr][t]; q += redQ[rr][t]; }
        *(float2*)&p1[(size_t)(rt * 256 + ch * 128 + t) * 2] = make_float2(s, q);
    }
}

// ============================================================================
// B: 256 blocks x 512 thr, 8 rows/block. BN1 stats (cached p1) -> BN1+ReLU ->
// h1 LDS -> GEMM2 (z2 in regs) -> p2 (uncached, 1KB/block) -> BAR(1) ->
// 16 leader blocks reduce p2 -> s2g -> BAR(2) -> BN2+W3 dot + yfm -> out.
// ============================================================================
__global__ __launch_bounds__(512) void kB_rest(
    const float* __restrict__ z1, const float* __restrict__ p1,
    const float* __restrict__ g1, const float* __restrict__ be1,
    const float* __restrict__ W2, const float* __restrict__ b2,
    const float* __restrict__ g2, const float* __restrict__ be2,
    const float* __restrict__ W3, const float* __restrict__ b3,
    const float* __restrict__ yfm,
    unsigned* __restrict__ flags, float* __restrict__ p2,
    float* __restrict__ s2g, float* __restrict__ out)
{
    __shared__ __align__(16) float h1s[8][256];
    __shared__ __align__(16) float sclS[256], shfS[256];
    __shared__ __align__(16) float sbuf[2][256], qbuf[2][256];
    __shared__ __align__(16) float redS[8][128], redQ[8][128];
    __shared__ float partS[8][8], partQ[8][8];

    const int t = threadIdx.x, blk = blockIdx.x;

    // ---- BN1 stats: 2 threads/col x 128 tiles each, cached coalesced loads
    {
        const int col = t & 255, h = t >> 8;
        float s = 0.f, q = 0.f;
#pragma unroll 16
        for (int i = 0; i < 128; ++i) {
            float2 v = *(const float2*)&p1[(size_t)((h * 128 + i) * 256 + col) * 2];
            s += v.x; q += v.y;
        }
        sbuf[h][col] = s; qbuf[h][col] = q;
    }
    __syncthreads();
    if (t < 256) {
        float s = sbuf[0][t] + sbuf[1][t];
        float q = qbuf[0][t] + qbuf[1][t];
        float mean = s * (1.f / 2048.f);
        float var  = q * (1.f / 2048.f) - mean * mean;
        float sc = g1[t] * __frsqrt_rn(var + EPS);
        sclS[t] = sc;
        shfS[t] = be1[t] - mean * sc;
    }
    __syncthreads();

    // ---- BN1+ReLU -> h1s
    {
        const int lr = t >> 6, lc = (t & 63) * 4;
        float4 zv = *(const float4*)&z1[(size_t)(blk * 8 + lr) * 256 + lc];
        float4 sc = *(const float4*)&sclS[lc];
        float4 sh = *(const float4*)&shfS[lc];
        float4 hv;
        hv.x = fmaxf(zv.x * sc.x + sh.x, 0.f);
        hv.y = fmaxf(zv.y * sc.y + sh.y, 0.f);
        hv.z = fmaxf(zv.z * sc.z + sh.z, 0.f);
        hv.w = fmaxf(zv.w * sc.w + sh.w, 0.f);
        *(float4*)&h1s[lr][lc] = hv;
    }
    __syncthreads();

    // ---- GEMM2: thread = row (t>>6) x cols {j, j+1}; z2 stays in registers
    const int r = t >> 6, j = (t & 63) * 2;
    float z2a, z2b;
    {
        float a0 = 0.f, a1 = 0.f;
#pragma unroll
        for (int k0 = 0; k0 < 256; k0 += 16) {
            float4 h[4];
#pragma unroll
            for (int i = 0; i < 4; ++i) h[i] = *(const float4*)&h1s[r][k0 + i * 4];
            float2 w[16];
#pragma unroll
            for (int kk = 0; kk < 16; ++kk)
                w[kk] = *(const float2*)&W2[(size_t)(k0 + kk) * 128 + j];
#pragma unroll
            for (int kk = 0; kk < 16; ++kk) {
                const float hv = ((const float*)h)[kk];
                a0 += hv * w[kk].x; a1 += hv * w[kk].y;
            }
        }
        float2 bv = *(const float2*)&b2[j];
        z2a = a0 + bv.x; z2b = a1 + bv.y;
    }
    *(float2*)&redS[r][j] = make_float2(z2a, z2b);
    *(float2*)&redQ[r][j] = make_float2(z2a * z2a, z2b * z2b);
    __syncthreads();
    if (t < 128) {
        float s = 0.f, q = 0.f;
#pragma unroll
        for (int rr = 0; rr < 8; ++rr) { s += redS[rr][t]; q += redQ[rr][t]; }
        st_f2(&p2[(size_t)(blk * 128 + t) * 2], s, q);
    }

    BARRIER(1);

    // ---- leaders: 16 blocks x 8 cols reduce p2 -> s2g (interleaved {scale,shift})
    if (blk < 16) {
        const int cc = t & 7, g = t >> 3;          // g in 0..63
        const int col = blk * 8 + cc;
        float s = 0.f, q = 0.f;
#pragma unroll
        for (int i = 0; i < 4; ++i) {
            float2 v = ld_f2(&p2[(size_t)((g + i * 64) * 128 + col) * 2]);
            s += v.x; q += v.y;
        }
#pragma unroll
        for (int m = 8; m <= 32; m <<= 1) {        // reduce g within wave
            s += __shfl_xor(s, m);
            q += __shfl_xor(q, m);
        }
        if ((t & 63) < 8) {
            partS[t >> 6][cc] = s;
            partQ[t >> 6][cc] = q;
        }
        __syncthreads();
        if (t < 8) {
            float fs = 0.f, fq = 0.f;
#pragma unroll
            for (int w = 0; w < 8; ++w) { fs += partS[w][t]; fq += partQ[w][t]; }
            const int c = blk * 8 + t;
            float mean = fs * (1.f / 2048.f);
            float var  = fq * (1.f / 2048.f) - mean * mean;
            float sc = g2[c] * __frsqrt_rn(var + EPS);
            st_f2(&s2g[2 * c], sc, be2[c] - mean * sc);
        }
    }

    BARRIER(2);

    // ---- BN2+ReLU, dot W3, output (wave = row, 64 lanes x 2 cols)
    {
        float2 sa = ld_f2(&s2g[2 * j]);
        float2 sb = ld_f2(&s2g[2 * (j + 1)]);
        float2 w3 = *(const float2*)&W3[j];
        float acc = fmaxf(z2a * sa.x + sa.y, 0.f) * w3.x
                  + fmaxf(z2b * sb.x + sb.y, 0.f) * w3.y;
#pragma unroll
        for (int m = 1; m <= 32; m <<= 1) acc += __shfl_xor(acc, m);
        if ((t & 63) == 0) out[blk * 8 + r] = acc + b3[0] + yfm[blk * 8 + r];
    }
}

extern "C" void kernel_launch(void* const* d_in, const int* in_sizes, int n_in,
                              void* d_out, int out_size, void* d_ws, size_t ws_size,
                              hipStream_t stream) {
    const int*   x    = (const int*)d_in[0];
    const float* emb  = (const float*)d_in[1];
    const float* wlin = (const float*)d_in[2];
    const float* blin = (const float*)d_in[3];
    const float* W1   = (const float*)d_in[4];
    const float* b1   = (const float*)d_in[5];
    const float* g1   = (const float*)d_in[6];
    const float* be1  = (const float*)d_in[7];
    const float* W2   = (const float*)d_in[8];
    const float* b2   = (const float*)d_in[9];
    const float* g2   = (const float*)d_in[10];
    const float* be2  = (const float*)d_in[11];
    const float* W3   = (const float*)d_in[12];
    const float* b3   = (const float*)d_in[13];

    float* ws  = (float*)d_ws;
    float* yfm = ws;                          // 2048
    float* z1  = yfm + 2048;                  // 2048*256
    float* p1  = z1 + 2048 * 256;             // 256 tiles x 256 cols x {s,q}
    float* p2  = p1 + 2 * 256 * 256;          // 256 tiles x 128 cols x {s,q}
    float* s2g = p2 + 2 * 256 * 128;          // 128 x {scale, shift}
    unsigned* flags = (unsigned*)(s2g + 256); // 256 flags
    float* out = (float*)d_out;

    kA_gather_fm_gemm1<<<512, 256, 0, stream>>>(x, emb, wlin, blin, W1, b1,
                                                yfm, z1, p1, flags);
    kB_rest<<<256, 512, 0, stream>>>(z1, p1, g1, be1, W2, b2, g2, be2, W3, b3,
                                     yfm, flags, p2, s2g, out);
}

// Round 9
// 48.828 us; speedup vs baseline: 1.1129x; 1.1129x over previous
//
#include <hip/hip_runtime.h>

#define EPS 1e-5f

static __device__ const int OFFS[8] = {0, 100000, 150000, 151000, 151500, 151600, 151650, 151670};

// ============================================================================
// K1 (identical to R7's proven kernel): 512 blocks x 256 thr.
// Block = (rt = blk>>1) 8 rows x (ch = blk&1) 128 cols.
// gather+FM (ch==0 writes yfm) -> h0 LDS -> GEMM1 (2r x 2c/thread, k-chunk 16)
// -> z1 + per-tile col partials p1[rt][col]{s,q}.
// ============================================================================
__global__ __launch_bounds__(256) void k1_gather_fm_gemm1(
    const int* __restrict__ x, const float* __restrict__ emb,
    const float* __restrict__ wlin, const float* __restrict__ blin,
    const float* __restrict__ W1, const float* __restrict__ b1,
    float* __restrict__ yfm, float* __restrict__ z1, float* __restrict__ p1)
{
    __shared__ __align__(16) float h0s[8][128];
    __shared__ __align__(16) float redS[8][128];
    __shared__ __align__(16) float redQ[8][128];

    const int t = threadIdx.x;
    const int rt = blockIdx.x >> 1, ch = blockIdx.x & 1;

    // ---- gather + FM: 32 threads/row
    {
        const int r = t >> 5, c = t & 31;
        const int row = rt * 8 + r;
        const int f = c >> 2, dq = (c & 3) * 4;
        const int idxf = x[row * 8 + f];
        float4 e = *(const float4*)&emb[(size_t)(idxf + OFFS[f]) * 16 + dq];
        *(float4*)&h0s[r][f * 16 + dq] = e;

        if (ch == 0) {
            float4 s = e;
            float4 q = make_float4(e.x * e.x, e.y * e.y, e.z * e.z, e.w * e.w);
#pragma unroll
            for (int m = 4; m <= 16; m <<= 1) {
                s.x += __shfl_xor(s.x, m); s.y += __shfl_xor(s.y, m);
                s.z += __shfl_xor(s.z, m); s.w += __shfl_xor(s.w, m);
                q.x += __shfl_xor(q.x, m); q.y += __shfl_xor(q.y, m);
                q.z += __shfl_xor(q.z, m); q.w += __shfl_xor(q.w, m);
            }
            float pair = (s.x * s.x - q.x) + (s.y * s.y - q.y)
                       + (s.z * s.z - q.z) + (s.w * s.w - q.w);
            pair += __shfl_xor(pair, 1);
            pair += __shfl_xor(pair, 2);

            float lin = 0.f;
            if (c < 8) {
                int ids[8];
#pragma unroll
                for (int g = 0; g < 8; ++g) ids[g] = x[row * 8 + g];
                bool dup = false;
                for (int g = 0; g < c; ++g) dup = dup || (ids[g] == ids[c]);
                lin = dup ? 0.f : wlin[ids[c]];
            }
            lin += __shfl_xor(lin, 1);
            lin += __shfl_xor(lin, 2);
            lin += __shfl_xor(lin, 4);
            if (c == 0) yfm[row] = 0.5f * pair + lin + blin[0];
        }
    }
    __syncthreads();

    // ---- GEMM1: thread = rows {rg*2, rg*2+1} x cols {j, j+1}; k-chunks of 16
    const int cc = t & 63, rg = t >> 6;
    const int j = ch * 128 + cc * 2;
    const int r0 = rg * 2;
    float a00 = 0.f, a01 = 0.f, a10 = 0.f, a11 = 0.f;
#pragma unroll
    for (int k0 = 0; k0 < 128; k0 += 16) {
        float4 ha[4], hb[4];
#pragma unroll
        for (int i = 0; i < 4; ++i) {
            ha[i] = *(const float4*)&h0s[r0][k0 + i * 4];
            hb[i] = *(const float4*)&h0s[r0 + 1][k0 + i * 4];
        }
        float2 w[16];
#pragma unroll
        for (int kk = 0; kk < 16; ++kk)
            w[kk] = *(const float2*)&W1[(size_t)(k0 + kk) * 256 + j];
#pragma unroll
        for (int kk = 0; kk < 16; ++kk) {
            const float hva = ((const float*)ha)[kk];
            const float hvb = ((const float*)hb)[kk];
            a00 += hva * w[kk].x; a01 += hva * w[kk].y;
            a10 += hvb * w[kk].x; a11 += hvb * w[kk].y;
        }
    }
    float2 b2v = *(const float2*)&b1[j];
    float z00 = a00 + b2v.x, z01 = a01 + b2v.y;
    float z10 = a10 + b2v.x, z11 = a11 + b2v.y;
    *(float2*)&z1[(size_t)(rt * 8 + r0) * 256 + j]     = make_float2(z00, z01);
    *(float2*)&z1[(size_t)(rt * 8 + r0 + 1) * 256 + j] = make_float2(z10, z11);
    *(float2*)&redS[r0][cc * 2]     = make_float2(z00, z01);
    *(float2*)&redS[r0 + 1][cc * 2] = make_float2(z10, z11);
    *(float2*)&redQ[r0][cc * 2]     = make_float2(z00 * z00, z01 * z01);
    *(float2*)&redQ[r0 + 1][cc * 2] = make_float2(z10 * z10, z11 * z11);
    __syncthreads();
    if (t < 128) {
        float s = 0.f, q = 0.f;
#pragma unroll
        for (int rr = 0; rr < 8; ++rr) { s += redS[rr][t]; q += redQ[rr][t]; }
        *(float2*)&p1[(size_t)(rt * 256 + ch * 128 + t) * 2] = make_float2(s, q);
    }
}

// ============================================================================
// K2: 256 blocks x 512 thr, 8 rows/block.
// Inline BN1 stats (redundant, cached, coalesced: 2 thr/col x 128 tiles) ->
// BN1+ReLU -> h1 LDS -> GEMM2 (1r x 2c/thread, k-chunk 16) -> z2 + p2 partials.
// ============================================================================
__global__ __launch_bounds__(512) void k2_bn1_gemm2(
    const float* __restrict__ z1, const float* __restrict__ p1,
    const float* __restrict__ g1, const float* __restrict__ be1,
    const float* __restrict__ W2, const float* __restrict__ b2,
    float* __restrict__ z2, float* __restrict__ p2)
{
    __shared__ __align__(16) float h1s[8][256];
    __shared__ __align__(16) float sclS[256], shfS[256];
    __shared__ __align__(16) float sbuf[2][256], qbuf[2][256];
    __shared__ __align__(16) float redS[8][128], redQ[8][128];

    const int t = threadIdx.x, blk = blockIdx.x;

    // ---- BN1 stats: wave-coalesced float2 reads of p1 (256 tiles x 256 cols)
    {
        const int col = t & 255, h = t >> 8;
        float s = 0.f, q = 0.f;
#pragma unroll 16
        for (int i = 0; i < 128; ++i) {
            float2 v = *(const float2*)&p1[(size_t)((h * 128 + i) * 256 + col) * 2];
            s += v.x; q += v.y;
        }
        sbuf[h][col] = s; qbuf[h][col] = q;
    }
    __syncthreads();
    if (t < 256) {
        float s = sbuf[0][t] + sbuf[1][t];
        float q = qbuf[0][t] + qbuf[1][t];
        float mean = s * (1.f / 2048.f);
        float var  = q * (1.f / 2048.f) - mean * mean;
        float sc = g1[t] * __frsqrt_rn(var + EPS);
        sclS[t] = sc;
        shfS[t] = be1[t] - mean * sc;
    }
    __syncthreads();

    // ---- BN1+ReLU -> h1s
    {
        const int lr = t >> 6, lc = (t & 63) * 4;
        float4 zv = *(const float4*)&z1[(size_t)(blk * 8 + lr) * 256 + lc];
        float4 sc = *(const float4*)&sclS[lc];
        float4 sh = *(const float4*)&shfS[lc];
        float4 hv;
        hv.x = fmaxf(zv.x * sc.x + sh.x, 0.f);
        hv.y = fmaxf(zv.y * sc.y + sh.y, 0.f);
        hv.z = fmaxf(zv.z * sc.z + sh.z, 0.f);
        hv.w = fmaxf(zv.w * sc.w + sh.w, 0.f);
        *(float4*)&h1s[lr][lc] = hv;
    }
    __syncthreads();

    // ---- GEMM2: thread = row (t>>6) x cols {j, j+1}; k-chunks of 16
    const int r = t >> 6, j = (t & 63) * 2;
    float a0 = 0.f, a1 = 0.f;
#pragma unroll
    for (int k0 = 0; k0 < 256; k0 += 16) {
        float4 h[4];
#pragma unroll
        for (int i = 0; i < 4; ++i) h[i] = *(const float4*)&h1s[r][k0 + i * 4];
        float2 w[16];
#pragma unroll
        for (int kk = 0; kk < 16; ++kk)
            w[kk] = *(const float2*)&W2[(size_t)(k0 + kk) * 128 + j];
#pragma unroll
        for (int kk = 0; kk < 16; ++kk) {
            const float hv = ((const float*)h)[kk];
            a0 += hv * w[kk].x; a1 += hv * w[kk].y;
        }
    }
    float2 bv = *(const float2*)&b2[j];
    float za = a0 + bv.x, zb = a1 + bv.y;
    *(float2*)&z2[(size_t)(blk * 8 + r) * 128 + j] = make_float2(za, zb);
    *(float2*)&redS[r][j] = make_float2(za, zb);
    *(float2*)&redQ[r][j] = make_float2(za * za, zb * zb);
    __syncthreads();
    if (t < 128) {
        float s = 0.f, q = 0.f;
#pragma unroll
        for (int rr = 0; rr < 8; ++rr) { s += redS[rr][t]; q += redQ[rr][t]; }
        *(float2*)&p2[(size_t)(blk * 128 + t) * 2] = make_float2(s, q);
    }
}

// ============================================================================
// K3: 256 blocks x 256 thr, 8 rows/block.
// Inline BN2 stats (redundant, cached: 2 thr/col x 128 tiles) -> BN2+ReLU ->
// dot W3 -> + yfm -> out.
// ============================================================================
__global__ __launch_bounds__(256) void k3_bn2_out(
    const float* __restrict__ z2, const float* __restrict__ p2,
    const float* __restrict__ g2, const float* __restrict__ be2,
    const float* __restrict__ W3, const float* __restrict__ b3,
    const float* __restrict__ yfm, float* __restrict__ out)
{
    __shared__ __align__(16) float sbuf[2][128], qbuf[2][128];
    __shared__ __align__(16) float scl[128], shf[128];

    const int t = threadIdx.x, blk = blockIdx.x;

    // ---- BN2 stats: 2 thr/col x 128 tiles, coalesced float2 reads
    {
        const int col = t & 127, h = t >> 7;
        float s = 0.f, q = 0.f;
#pragma unroll 16
        for (int i = 0; i < 128; ++i) {
            float2 v = *(const float2*)&p2[(size_t)((h * 128 + i) * 128 + col) * 2];
            s += v.x; q += v.y;
        }
        sbuf[h][col] = s; qbuf[h][col] = q;
    }
    __syncthreads();
    if (t < 128) {
        float s = sbuf[0][t] + sbuf[1][t];
        float q = qbuf[0][t] + qbuf[1][t];
        float mean = s * (1.f / 2048.f);
        float var  = q * (1.f / 2048.f) - mean * mean;
        float sc = g2[t] * __frsqrt_rn(var + EPS);
        scl[t] = sc;
        shf[t] = be2[t] - mean * sc;
    }
    __syncthreads();

    // ---- output: 32 threads/row, 4 dims each
    const int r = t >> 5, l = t & 31;
    const int b = blk * 8 + r;
    float4 zv = *(const float4*)&z2[(size_t)b * 128 + l * 4];
    float4 sc = *(const float4*)&scl[l * 4];
    float4 sh = *(const float4*)&shf[l * 4];
    float4 wv = *(const float4*)&W3[l * 4];
    float acc = fmaxf(zv.x * sc.x + sh.x, 0.f) * wv.x
              + fmaxf(zv.y * sc.y + sh.y, 0.f) * wv.y
              + fmaxf(zv.z * sc.z + sh.z, 0.f) * wv.z
              + fmaxf(zv.w * sc.w + sh.w, 0.f) * wv.w;
#pragma unroll
    for (int m = 16; m >= 1; m >>= 1) acc += __shfl_xor(acc, m);
    if (l == 0) out[b] = acc + b3[0] + yfm[b];
}

extern "C" void kernel_launch(void* const* d_in, const int* in_sizes, int n_in,
                              void* d_out, int out_size, void* d_ws, size_t ws_size,
                              hipStream_t stream) {
    const int*   x    = (const int*)d_in[0];
    const float* emb  = (const float*)d_in[1];
    const float* wlin = (const float*)d_in[2];
    const float* blin = (const float*)d_in[3];
    const float* W1   = (const float*)d_in[4];
    const float* b1   = (const float*)d_in[5];
    const float* g1   = (const float*)d_in[6];
    const float* be1  = (const float*)d_in[7];
    const float* W2   = (const float*)d_in[8];
    const float* b2   = (const float*)d_in[9];
    const float* g2   = (const float*)d_in[10];
    const float* be2  = (const float*)d_in[11];
    const float* W3   = (const float*)d_in[12];
    const float* b3   = (const float*)d_in[13];

    float* ws  = (float*)d_ws;
    float* yfm = ws;                          // 2048
    float* z1  = yfm + 2048;                  // 2048*256
    float* p1  = z1 + 2048 * 256;             // 256 tiles x 256 cols x {s,q}
    float* z2  = p1 + 2 * 256 * 256;          // 2048*128
    float* p2  = z2 + 2048 * 128;             // 256 tiles x 128 cols x {s,q}
    float* out = (float*)d_out;

    k1_gather_fm_gemm1<<<512, 256, 0, stream>>>(x, emb, wlin, blin, W1, b1, yfm, z1, p1);
    k2_bn1_gemm2<<<256, 512, 0, stream>>>(z1, p1, g1, be1, W2, b2, z2, p2);
    k3_bn2_out<<<256, 256, 0, stream>>>(z2, p2, g2, be2, W3, b3, yfm, out);
}

// Round 10
// 38.389 us; speedup vs baseline: 1.4155x; 1.2719x over previous
//
#include <hip/hip_runtime.h>

#define EPS 1e-5f

static __device__ const int OFFS[8] = {0, 100000, 150000, 151000, 151500, 151600, 151650, 151670};

// ============================================================================
// K1: 256 blocks x 256 thr. Block = (rt = blk>>1) 16 rows x (ch = blk&1) 128 cols.
// gather+FM (ch==0 writes yfm) -> h0 LDS -> GEMM1 (4r x 2c/thread, k-chunk 16)
// -> z1 + per-tile col partials p1 (128 tiles x 256 cols x {s,q}).
// ============================================================================
__global__ __launch_bounds__(256) void k1_gather_fm_gemm1(
    const int* __restrict__ x, const float* __restrict__ emb,
    const float* __restrict__ wlin, const float* __restrict__ blin,
    const float* __restrict__ W1, const float* __restrict__ b1,
    float* __restrict__ yfm, float* __restrict__ z1, float* __restrict__ p1)
{
    __shared__ __align__(16) float h0s[16][128];
    __shared__ __align__(16) float redS[16][128];
    __shared__ __align__(16) float redQ[16][128];

    const int t = threadIdx.x;
    const int rt = blockIdx.x >> 1, ch = blockIdx.x & 1;

    // ---- gather + FM: 16 threads/row; thread (f = u>>1, dq = (u&1)*8) loads 8 dims
    {
        const int r = t >> 4, u = t & 15;
        const int row = rt * 16 + r;
        const int f = u >> 1, dq = (u & 1) * 8;
        const int idxf = x[row * 8 + f];
        const size_t base = (size_t)(idxf + OFFS[f]) * 16 + dq;
        float4 e0 = *(const float4*)&emb[base];
        float4 e1 = *(const float4*)&emb[base + 4];
        *(float4*)&h0s[r][f * 16 + dq]     = e0;
        *(float4*)&h0s[r][f * 16 + dq + 4] = e1;

        if (ch == 0) {
            float s[8] = {e0.x, e0.y, e0.z, e0.w, e1.x, e1.y, e1.z, e1.w};
            float q[8];
#pragma unroll
            for (int d = 0; d < 8; ++d) q[d] = s[d] * s[d];
            // sum over fields: u bits 1..3 -> lane masks 2,4,8 (stay in 16-lane group)
#pragma unroll
            for (int m = 2; m <= 8; m <<= 1) {
#pragma unroll
                for (int d = 0; d < 8; ++d) {
                    s[d] += __shfl_xor(s[d], m);
                    q[d] += __shfl_xor(q[d], m);
                }
            }
            float pair = 0.f;
#pragma unroll
            for (int d = 0; d < 8; ++d) pair += s[d] * s[d] - q[d];
            pair += __shfl_xor(pair, 1);   // combine the two dq-halves

            float lin = 0.f;
            if (u < 8) {
                int ids[8];
#pragma unroll
                for (int g = 0; g < 8; ++g) ids[g] = x[row * 8 + g];
                bool dup = false;
                for (int g = 0; g < u; ++g) dup = dup || (ids[g] == ids[u]);
                lin = dup ? 0.f : wlin[ids[u]];
            }
            lin += __shfl_xor(lin, 1);
            lin += __shfl_xor(lin, 2);
            lin += __shfl_xor(lin, 4);
            if (u == 0) yfm[row] = 0.5f * pair + lin + blin[0];
        }
    }
    __syncthreads();

    // ---- GEMM1: thread = rows {rg*4..rg*4+3} x cols {j, j+1}; k-chunks of 16
    const int cc = t & 63, rg = t >> 6;
    const int j = ch * 128 + cc * 2;
    const int r0 = rg * 4;
    float a[4][2] = {{0.f,0.f},{0.f,0.f},{0.f,0.f},{0.f,0.f}};
#pragma unroll
    for (int k0 = 0; k0 < 128; k0 += 16) {
        float2 w[16];
#pragma unroll
        for (int kk = 0; kk < 16; ++kk)
            w[kk] = *(const float2*)&W1[(size_t)(k0 + kk) * 256 + j];
        float4 h[4][4];
#pragma unroll
        for (int rr = 0; rr < 4; ++rr)
#pragma unroll
            for (int i = 0; i < 4; ++i)
                h[rr][i] = *(const float4*)&h0s[r0 + rr][k0 + i * 4];
#pragma unroll
        for (int kk = 0; kk < 16; ++kk) {
#pragma unroll
            for (int rr = 0; rr < 4; ++rr) {
                const float hv = ((const float*)h[rr])[kk];
                a[rr][0] += hv * w[kk].x;
                a[rr][1] += hv * w[kk].y;
            }
        }
    }
    float2 bv = *(const float2*)&b1[j];
#pragma unroll
    for (int rr = 0; rr < 4; ++rr) {
        float z0 = a[rr][0] + bv.x, z1v = a[rr][1] + bv.y;
        *(float2*)&z1[(size_t)(rt * 16 + r0 + rr) * 256 + j] = make_float2(z0, z1v);
        *(float2*)&redS[r0 + rr][cc * 2] = make_float2(z0, z1v);
        *(float2*)&redQ[r0 + rr][cc * 2] = make_float2(z0 * z0, z1v * z1v);
    }
    __syncthreads();
    if (t < 128) {
        float s = 0.f, q = 0.f;
#pragma unroll
        for (int rr = 0; rr < 16; ++rr) { s += redS[rr][t]; q += redQ[rr][t]; }
        *(float2*)&p1[(size_t)(rt * 256 + ch * 128 + t) * 2] = make_float2(s, q);
    }
}

// ============================================================================
// K2: 128 blocks x 512 thr, 16 rows/block. Redundant BN1 stats from p1
// (128 tiles, 256 KB/block cached) -> BN1+ReLU -> h1 LDS -> GEMM2
// (2r x 2c/thread, k-chunk 16) -> z2 + p2 partials (128 tiles).
// ============================================================================
__global__ __launch_bounds__(512) void k2_bn1_gemm2(
    const float* __restrict__ z1, const float* __restrict__ p1,
    const float* __restrict__ g1, const float* __restrict__ be1,
    const float* __restrict__ W2, const float* __restrict__ b2,
    float* __restrict__ z2, float* __restrict__ p2)
{
    __shared__ __align__(16) float h1s[16][256];
    __shared__ __align__(16) float sclS[256], shfS[256];
    __shared__ __align__(16) float sbuf[2][256], qbuf[2][256];
    __shared__ __align__(16) float redS[16][128], redQ[16][128];

    const int t = threadIdx.x, blk = blockIdx.x;

    // ---- BN1 stats: 2 thr/col x 64 tiles each, coalesced float2 reads
    {
        const int col = t & 255, h = t >> 8;
        float s = 0.f, q = 0.f;
#pragma unroll 16
        for (int i = 0; i < 64; ++i) {
            float2 v = *(const float2*)&p1[(size_t)((h * 64 + i) * 256 + col) * 2];
            s += v.x; q += v.y;
        }
        sbuf[h][col] = s; qbuf[h][col] = q;
    }
    __syncthreads();
    if (t < 256) {
        float s = sbuf[0][t] + sbuf[1][t];
        float q = qbuf[0][t] + qbuf[1][t];
        float mean = s * (1.f / 2048.f);
        float var  = q * (1.f / 2048.f) - mean * mean;
        float sc = g1[t] * __frsqrt_rn(var + EPS);
        sclS[t] = sc;
        shfS[t] = be1[t] - mean * sc;
    }
    __syncthreads();

    // ---- BN1+ReLU -> h1s: 512 thr x 8 elems (2x float4)
    {
        const int lr = t >> 5, lc = (t & 31) * 8;
#pragma unroll
        for (int half = 0; half < 2; ++half) {
            const int c = lc + half * 4;
            float4 zv = *(const float4*)&z1[(size_t)(blk * 16 + lr) * 256 + c];
            float4 sc = *(const float4*)&sclS[c];
            float4 sh = *(const float4*)&shfS[c];
            float4 hv;
            hv.x = fmaxf(zv.x * sc.x + sh.x, 0.f);
            hv.y = fmaxf(zv.y * sc.y + sh.y, 0.f);
            hv.z = fmaxf(zv.z * sc.z + sh.z, 0.f);
            hv.w = fmaxf(zv.w * sc.w + sh.w, 0.f);
            *(float4*)&h1s[lr][c] = hv;
        }
    }
    __syncthreads();

    // ---- GEMM2: thread = rows {rg*2, rg*2+1} x cols {j, j+1}; k-chunks of 16
    const int rg = t >> 6, j = (t & 63) * 2;
    const int r0 = rg * 2;
    float a00 = 0.f, a01 = 0.f, a10 = 0.f, a11 = 0.f;
#pragma unroll
    for (int k0 = 0; k0 < 256; k0 += 16) {
        float2 w[16];
#pragma unroll
        for (int kk = 0; kk < 16; ++kk)
            w[kk] = *(const float2*)&W2[(size_t)(k0 + kk) * 128 + j];
        float4 ha[4], hb[4];
#pragma unroll
        for (int i = 0; i < 4; ++i) {
            ha[i] = *(const float4*)&h1s[r0][k0 + i * 4];
            hb[i] = *(const float4*)&h1s[r0 + 1][k0 + i * 4];
        }
#pragma unroll
        for (int kk = 0; kk < 16; ++kk) {
            const float hva = ((const float*)ha)[kk];
            const float hvb = ((const float*)hb)[kk];
            a00 += hva * w[kk].x; a01 += hva * w[kk].y;
            a10 += hvb * w[kk].x; a11 += hvb * w[kk].y;
        }
    }
    float2 bv = *(const float2*)&b2[j];
    float z00 = a00 + bv.x, z01 = a01 + bv.y;
    float z10 = a10 + bv.x, z11 = a11 + bv.y;
    *(float2*)&z2[(size_t)(blk * 16 + r0) * 128 + j]     = make_float2(z00, z01);
    *(float2*)&z2[(size_t)(blk * 16 + r0 + 1) * 128 + j] = make_float2(z10, z11);
    *(float2*)&redS[r0][j]     = make_float2(z00, z01);
    *(float2*)&redS[r0 + 1][j] = make_float2(z10, z11);
    *(float2*)&redQ[r0][j]     = make_float2(z00 * z00, z01 * z01);
    *(float2*)&redQ[r0 + 1][j] = make_float2(z10 * z10, z11 * z11);
    __syncthreads();
    if (t < 128) {
        float s = 0.f, q = 0.f;
#pragma unroll
        for (int rr = 0; rr < 16; ++rr) { s += redS[rr][t]; q += redQ[rr][t]; }
        *(float2*)&p2[(size_t)(blk * 128 + t) * 2] = make_float2(s, q);
    }
}

// ============================================================================
// K3: 128 blocks x 256 thr, 16 rows/block. Redundant BN2 stats from p2
// (128 tiles, 128 KB/block cached) -> BN2+ReLU -> dot W3 -> + yfm -> out.
// ============================================================================
__global__ __launch_bounds__(256) void k3_bn2_out(
    const float* __restrict__ z2, const float* __restrict__ p2,
    const float* __restrict__ g2, const float* __restrict__ be2,
    const float* __restrict__ W3, const float* __restrict__ b3,
    const float* __restrict__ yfm, float* __restrict__ out)
{
    __shared__ __align__(16) float sbuf[2][128], qbuf[2][128];
    __shared__ __align__(16) float scl[128], shf[128];

    const int t = threadIdx.x, blk = blockIdx.x;

    // ---- BN2 stats: 2 thr/col x 64 tiles each
    {
        const int col = t & 127, h = t >> 7;
        float s = 0.f, q = 0.f;
#pragma unroll 16
        for (int i = 0; i < 64; ++i) {
            float2 v = *(const float2*)&p2[(size_t)((h * 64 + i) * 128 + col) * 2];
            s += v.x; q += v.y;
        }
        sbuf[h][col] = s; qbuf[h][col] = q;
    }
    __syncthreads();
    if (t < 128) {
        float s = sbuf[0][t] + sbuf[1][t];
        float q = qbuf[0][t] + qbuf[1][t];
        float mean = s * (1.f / 2048.f);
        float var  = q * (1.f / 2048.f) - mean * mean;
        float sc = g2[t] * __frsqrt_rn(var + EPS);
        scl[t] = sc;
        shf[t] = be2[t] - mean * sc;
    }
    __syncthreads();

    // ---- output: 16 threads/row, 8 dims each
    const int r = t >> 4, u = t & 15;
    const int b = blk * 16 + r;
    float acc = 0.f;
#pragma unroll
    for (int half = 0; half < 2; ++half) {
        const int c = u * 8 + half * 4;
        float4 zv = *(const float4*)&z2[(size_t)b * 128 + c];
        float4 sc = *(const float4*)&scl[c];
        float4 sh = *(const float4*)&shf[c];
        float4 wv = *(const float4*)&W3[c];
        acc += fmaxf(zv.x * sc.x + sh.x, 0.f) * wv.x
             + fmaxf(zv.y * sc.y + sh.y, 0.f) * wv.y
             + fmaxf(zv.z * sc.z + sh.z, 0.f) * wv.z
             + fmaxf(zv.w * sc.w + sh.w, 0.f) * wv.w;
    }
#pragma unroll
    for (int m = 8; m >= 1; m >>= 1) acc += __shfl_xor(acc, m);
    if (u == 0) out[b] = acc + b3[0] + yfm[b];
}

extern "C" void kernel_launch(void* const* d_in, const int* in_sizes, int n_in,
                              void* d_out, int out_size, void* d_ws, size_t ws_size,
                              hipStream_t stream) {
    const int*   x    = (const int*)d_in[0];
    const float* emb  = (const float*)d_in[1];
    const float* wlin = (const float*)d_in[2];
    const float* blin = (const float*)d_in[3];
    const float* W1   = (const float*)d_in[4];
    const float* b1   = (const float*)d_in[5];
    const float* g1   = (const float*)d_in[6];
    const float* be1  = (const float*)d_in[7];
    const float* W2   = (const float*)d_in[8];
    const float* b2   = (const float*)d_in[9];
    const float* g2   = (const float*)d_in[10];
    const float* be2  = (const float*)d_in[11];
    const float* W3   = (const float*)d_in[12];
    const float* b3   = (const float*)d_in[13];

    float* ws  = (float*)d_ws;
    float* yfm = ws;                          // 2048
    float* z1  = yfm + 2048;                  // 2048*256
    float* p1  = z1 + 2048 * 256;             // 128 tiles x 256 cols x {s,q}
    float* z2  = p1 + 2 * 128 * 256;          // 2048*128
    float* p2  = z2 + 2048 * 128;             // 128 tiles x 128 cols x {s,q}
    float* out = (float*)d_out;

    k1_gather_fm_gemm1<<<256, 256, 0, stream>>>(x, emb, wlin, blin, W1, b1, yfm, z1, p1);
    k2_bn1_gemm2<<<128, 512, 0, stream>>>(z1, p1, g1, be1, W2, b2, z2, p2);
    k3_bn2_out<<<128, 256, 0, stream>>>(z2, p2, g2, be2, W3, b3, yfm, out);
}